// Round 1
// baseline (397.799 us; speedup 1.0000x reference)
//
#include <hip/hip_runtime.h>

// VoxelFeatureEncoding: voxels[20000,35,4] -> out[20000,35,128]
// out[:, :, :64]  = relu(BN(aug @ W^T + b)),  aug = [v, v[:3]-mean3]
// out[:, :, 64:]  = broadcast(max over T of first half)
//
// BN batch stats computed exactly via 7x7 second-moment matrix of aug
// (linearity of the 7->64 layer), so pass 1 touches only the 11 MB input.

#define NVOX   20000
#define TDIM   35
#define NCH    128
#define HID    64
#define NTF    700000.0f      // N*T, exact in fp32
#define EPS    1e-5f
#define NBLK_A 256
#define SCALE_OFF (NBLK_A * 35)        // ws float offsets
#define SHIFT_OFF (NBLK_A * 35 + 64)   // total ws need: (256*35+128)*4 = 36352 B

// ---------------- pass 1: per-block partial [M2(28) | s(7)] ----------------
__global__ __launch_bounds__(256) void vfe_stats(const float* __restrict__ vox,
                                                 float* __restrict__ ws) {
  const int lane = threadIdx.x & 63;
  const int wid  = threadIdx.x >> 6;
  const int gwave  = (blockIdx.x * 256 + threadIdx.x) >> 6;
  const int nwaves = NBLK_A * 4;

  float m2[28], sv[7];
#pragma unroll
  for (int i = 0; i < 28; ++i) m2[i] = 0.f;
#pragma unroll
  for (int i = 0; i < 7; ++i) sv[i] = 0.f;

  for (int n = gwave; n < NVOX; n += nwaves) {
    float4 row = make_float4(0.f, 0.f, 0.f, 0.f);
    if (lane < TDIM) row = *(const float4*)(vox + (size_t)n * (TDIM * 4) + lane * 4);
    float rowsum = (row.x + row.y) + (row.z + row.w);
    float cnt = (float)__popcll(__ballot((lane < TDIM) && (rowsum != 0.f)));
    float s0 = row.x, s1 = row.y, s2 = row.z;
#pragma unroll
    for (int off = 32; off; off >>= 1) {
      s0 += __shfl_down(s0, off);
      s1 += __shfl_down(s1, off);
      s2 += __shfl_down(s2, off);
    }
    float mx = __shfl(s0, 0) / cnt;
    float my = __shfl(s1, 0) / cnt;
    float mz = __shfl(s2, 0) / cnt;
    if (lane < TDIM) {
      float a[7] = {row.x, row.y, row.z, row.w, row.x - mx, row.y - my, row.z - mz};
      int idx = 0;
#pragma unroll
      for (int j = 0; j < 7; ++j) {
        sv[j] += a[j];
#pragma unroll
        for (int k = j; k < 7; ++k) { m2[idx] = fmaf(a[j], a[k], m2[idx]); ++idx; }
      }
    }
  }

  __shared__ float part[4][35];
#pragma unroll
  for (int i = 0; i < 35; ++i) {
    float v = (i < 28) ? m2[i] : sv[i - 28];
#pragma unroll
    for (int off = 32; off; off >>= 1) v += __shfl_down(v, off);
    if (lane == 0) part[wid][i] = v;
  }
  __syncthreads();
  if (threadIdx.x < 35)
    ws[blockIdx.x * 35 + threadIdx.x] =
        part[0][threadIdx.x] + part[1][threadIdx.x] +
        part[2][threadIdx.x] + part[3][threadIdx.x];
}

// ------------- pass 2: fold BN + bias into per-channel scale/shift ---------
__global__ void vfe_bnparams(const float* __restrict__ W, const float* __restrict__ b,
                             const float* __restrict__ gamma, const float* __restrict__ beta,
                             float* __restrict__ ws) {
  __shared__ float stats[35];
  for (int i = threadIdx.x; i < 35; i += 64) {
    float acc = 0.f;
    for (int p = 0; p < NBLK_A; ++p) acc += ws[p * 35 + i];
    stats[i] = acc;
  }
  __syncthreads();

  const int c = threadIdx.x;
  float m2[7][7];
  {
    int idx = 0;
    for (int j = 0; j < 7; ++j)
      for (int k = j; k < 7; ++k) { float v = stats[idx++]; m2[j][k] = v; m2[k][j] = v; }
  }
  float w[7];
#pragma unroll
  for (int j = 0; j < 7; ++j) w[j] = W[c * 7 + j];
  float bc = b[c];

  float wdots = 0.f;
#pragma unroll
  for (int j = 0; j < 7; ++j) wdots = fmaf(w[j], stats[28 + j], wdots);
  float q = 0.f;
#pragma unroll
  for (int j = 0; j < 7; ++j) {
    float t = 0.f;
#pragma unroll
    for (int k = 0; k < 7; ++k) t = fmaf(w[k], m2[j][k], t);
    q = fmaf(w[j], t, q);
  }
  float sx  = wdots + NTF * bc;                       // sum x_c
  float sxx = q + 2.f * bc * wdots + NTF * bc * bc;   // sum x_c^2
  float mu  = sx / NTF;
  float var = sxx / NTF - mu * mu;                    // biased, as reference
  float scale = gamma[c] / sqrtf(var + EPS);
  float shift = beta[c] + scale * (bc - mu);          // bias folded in
  ws[SCALE_OFF + c] = scale;
  ws[SHIFT_OFF + c] = shift;
}

// --------- pass 3: wave-per-voxel, lane = channel, write 358 MB out --------
__global__ __launch_bounds__(256) void vfe_encode(const float* __restrict__ vox,
                                                  const float* __restrict__ W,
                                                  const float* __restrict__ ws,
                                                  float* __restrict__ out) {
  const int lane = threadIdx.x & 63;
  const int n = (blockIdx.x * 256 + threadIdx.x) >> 6;
  if (n >= NVOX) return;

  float4 row = make_float4(0.f, 0.f, 0.f, 0.f);
  if (lane < TDIM) row = *(const float4*)(vox + (size_t)n * (TDIM * 4) + lane * 4);
  float rowsum = (row.x + row.y) + (row.z + row.w);
  float cnt = (float)__popcll(__ballot((lane < TDIM) && (rowsum != 0.f)));
  float s0 = row.x, s1 = row.y, s2 = row.z;
#pragma unroll
  for (int off = 32; off; off >>= 1) {
    s0 += __shfl_down(s0, off);
    s1 += __shfl_down(s1, off);
    s2 += __shfl_down(s2, off);
  }
  const float r4 = row.x - __shfl(s0, 0) / cnt;   // rel coords, lane's own row
  const float r5 = row.y - __shfl(s1, 0) / cnt;
  const float r6 = row.z - __shfl(s2, 0) / cnt;

  const float w0 = W[lane * 7 + 0], w1 = W[lane * 7 + 1], w2 = W[lane * 7 + 2],
              w3 = W[lane * 7 + 3], w4 = W[lane * 7 + 4], w5 = W[lane * 7 + 5],
              w6 = W[lane * 7 + 6];
  const float scale = ws[SCALE_OFF + lane];
  const float shift = ws[SHIFT_OFF + lane];

  float* op = out + (size_t)n * (TDIM * NCH) + lane;
  float agg = 0.f;  // post-ReLU values are >= 0, so 0 is a valid identity
#pragma unroll
  for (int t = 0; t < TDIM; ++t) {
    float d = w0 * __shfl(row.x, t);
    d = fmaf(w1, __shfl(row.y, t), d);
    d = fmaf(w2, __shfl(row.z, t), d);
    d = fmaf(w3, __shfl(row.w, t), d);
    d = fmaf(w4, __shfl(r4, t), d);
    d = fmaf(w5, __shfl(r5, t), d);
    d = fmaf(w6, __shfl(r6, t), d);
    float y = fmaf(d, scale, shift);
    y = fmaxf(y, 0.f);
    agg = fmaxf(agg, y);
    op[t * NCH] = y;                 // 64 consecutive floats/wave: dense 256 B
  }
#pragma unroll
  for (int t = 0; t < TDIM; ++t) op[t * NCH + HID] = agg;
}

extern "C" void kernel_launch(void* const* d_in, const int* in_sizes, int n_in,
                              void* d_out, int out_size, void* d_ws, size_t ws_size,
                              hipStream_t stream) {
  const float* vox   = (const float*)d_in[0];
  const float* W     = (const float*)d_in[1];
  const float* b     = (const float*)d_in[2];
  const float* gamma = (const float*)d_in[3];
  const float* beta  = (const float*)d_in[4];
  float* out = (float*)d_out;
  float* ws  = (float*)d_ws;

  vfe_stats<<<NBLK_A, 256, 0, stream>>>(vox, ws);
  vfe_bnparams<<<1, 64, 0, stream>>>(W, b, gamma, beta, ws);
  vfe_encode<<<(NVOX * 64) / 256, 256, 0, stream>>>(vox, W, ws, out);
}